// Round 16
// baseline (123.991 us; speedup 1.0000x reference)
//
#include <hip/hip_runtime.h>
#include <hip/hip_bf16.h>

#define BATCH 131072
#define PITCH_H 72   // half-tile row: 64 + 8 pad bf16 (144 B = 9x16B; rows stay 16B-aligned)

typedef __bf16 bf16x4 __attribute__((ext_vector_type(4)));
typedef __bf16 bf16x8 __attribute__((ext_vector_type(8)));
typedef float floatx4 __attribute__((ext_vector_type(4)));

// Weights carry the tanh's factor 2 (exact in FP: bf16(2w) == 2*bf16(w)), so
// the GEMM output y equals 2*preact bit-exactly and tanh needs no input mul:
// tanh = 1 - 2/(exp(y)+1); exp overflow -> inf -> rcp -> 0 -> +1 (correct limit)
__device__ __forceinline__ float fast_tanh2(float y) {
    float e = __expf(y);
    return 1.0f - 2.0f * __builtin_amdgcn_rcpf(e + 1.0f);
}

// Fragment index: f = (kb*128 + n)*4 + q  <->  M[k = kb*32 + q*8 + j][n], j=0..7.
// STORAGE SLOT (bank-deconflict, R16): slot(f) = f ^ ((f>>7)&7).
//  - R15's identity layout: write bank-slot = 4(n&1)+q_s, constant across a
//    16-lane tr-group -> 16-way conflict (3.67M cycles measured).
//  - XOR folds bits 7-9 (vary with tc) into the bank bits; plus nnr rotation
//    (n parity alternates) -> ~2-way == free (G4/m136).
//  - Reader: ((f>>7)&7) == (4*kb + (nt>>1))&7, lane-independent and
//    compile-time in the unrolled GEMM loops -> zero-cost constant XOR.
// Operand-swap symmetry: A-frag of M^T == B-frag of M for mfma_16x16x32.
//
// Structure rationale (rounds 0-15 evidence):
//  - R15 proved single-launch drops fixed overhead ~9us (59.5 -> 50.6) but
//    its staging writes bank-conflicted 16-way (+22us cnf). This round keeps
//    the single launch and fixes the conflicts (see above).
//  - All other levers measured: occupancy null (R7), stagger null (R9),
//    LDS-share +2 (R10), operand-swap +4.4 (R11), DMA staging +1.9 (R12),
//    VALU-count null (R13), I-cache null (R14).
//  - LDS = 32(W2)+32(GT)+9(tiles)+0.5(b2) = 73.5 KB -> 2 blocks/CU.
//  - launch_bounds(256,2) ONLY: budget-256 is the proven spill-free regime.
//    min-waves>=4 attrs -> 64-VGPR acc-split + ~200 MB scratch (R1/R2).
__global__ __launch_bounds__(256, 2) void cnf_main(
        const float* __restrict__ z, const float* __restrict__ t_ptr,
        const float* __restrict__ W1g, const float* __restrict__ b1g,
        const float* __restrict__ W2g, const float* __restrict__ b2g,
        const float* __restrict__ W3g, const float* __restrict__ b3g,
        float* __restrict__ out) {
    __shared__ __bf16 sW2s[16384];                             // 32 KB
    __shared__ __bf16 sGTs[16384];                             // 32 KB
    __shared__ float sb2f[128];                                // 512 B (holds 2*b2)
    __shared__ __align__(16) __bf16 tile[4][16 * PITCH_H];     // 9 KB

    const int tid = threadIdx.x;
    const int lane = tid & 63;
    const int w = tid >> 6;
    const int p = lane & 15;       // sample index (C/D col in all GEMMs)
    const int q = lane >> 4;       // quad (C/D row group)
    const float tval = t_ptr[0];

    // staging-tile coords: thread handles k in [k0,k0+8) x n in [n0,n0+8)
    const int tr = tid >> 4, tc = tid & 15;
    const int k0 = tr * 8, n0 = tc * 8;
    const int kb_s = tr >> 2, q_s = tr & 3;   // k0..k0+7 spans ONE swizzle octet

    // ---- hoisted data loads ----
    // z for it 0 (q==0 lanes)
    float4 zc0a, zc1a, zc0b, zc1b;
    {
        const int sb0 = blockIdx.x * 256 + w * 32;
        if (q == 0) {
            const float4* zp0 = (const float4*)(z + (size_t)(sb0 + p) * 8);
            const float4* zp1 = (const float4*)(z + (size_t)(sb0 + 16 + p) * 8);
            zc0a = zp0[0]; zc1a = zp0[1]; zc0b = zp1[0]; zc1b = zp1[1];
        }
    }

    // w1f from raw W1/b1 (x2 fold; bias hi/lo in K-slots 9/10) - bit-identical
    bf16x8 w1f[8];
    #pragma unroll
    for (int nt = 0; nt < 8; ++nt) {
        const int n = nt * 16 + p;
        bf16x8 v;
        #pragma unroll
        for (int j = 0; j < 8; ++j) v[j] = (__bf16)0.0f;
        if (q == 0) {
            #pragma unroll
            for (int j = 0; j < 8; ++j) v[j] = (__bf16)(2.0f * W1g[j * 128 + n]);
        } else if (q == 1) {
            v[0] = (__bf16)(2.0f * W1g[8 * 128 + n]);
            const float b2x = 2.0f * b1g[n];
            const float hi = (float)(__bf16)b2x;
            v[1] = (__bf16)b2x;          // bias hi
            v[2] = (__bf16)(b2x - hi);   // bias lo
        }
        w1f[nt] = v;
    }
    // w3f from raw W3 (unscaled; n=p<8 real, else 0)
    bf16x8 w3f[4];
    #pragma unroll
    for (int kb = 0; kb < 4; ++kb) {
        bf16x8 v;
        #pragma unroll
        for (int j = 0; j < 8; ++j)
            v[j] = (p < 8) ? (__bf16)W3g[(kb * 32 + q * 8 + j) * 8 + p] : (__bf16)0.0f;
        w3f[kb] = v;
    }
    floatx4 b3f = {0.f, 0.f, 0.f, 0.f};
    if (q < 2) b3f = *(const floatx4*)(b3g + q * 4);   // dz rows q*4+r (real d<8)
    if (tid < 128) sb2f[tid] = 2.0f * b2g[tid];        // x2 fold

    // ---- Phase A: GT staging. GT[k][n] = W2[n][k] * C[k][n], C = W3@W1 ----
    {
        float w3blk[8][8];                 // W3 rows k0..k0+7 (contiguous 256 B)
        #pragma unroll
        for (int j = 0; j < 8; ++j) {
            const float4 a = *(const float4*)(W3g + (k0 + j) * 8);
            const float4 b = *(const float4*)(W3g + (k0 + j) * 8 + 4);
            w3blk[j][0] = a.x; w3blk[j][1] = a.y; w3blk[j][2] = a.z; w3blk[j][3] = a.w;
            w3blk[j][4] = b.x; w3blk[j][5] = b.y; w3blk[j][6] = b.z; w3blk[j][7] = b.w;
        }
        #pragma unroll
        for (int nn = 0; nn < 8; ++nn) {
            const int nnr = (nn + tc) & 7;          // rotate: n parity varies in tr-group
            const int n = n0 + nnr;
            float w1c[8];
            #pragma unroll
            for (int d = 0; d < 8; ++d) w1c[d] = W1g[d * 128 + n];
            const float4 g0 = *(const float4*)(W2g + n * 128 + k0);
            const float4 g1 = *(const float4*)(W2g + n * 128 + k0 + 4);
            const float w2gt[8] = {g0.x, g0.y, g0.z, g0.w, g1.x, g1.y, g1.z, g1.w};
            bf16x8 v;
            #pragma unroll
            for (int j = 0; j < 8; ++j) {
                float c = 0.0f;
                #pragma unroll
                for (int d = 0; d < 8; ++d) c = __builtin_fmaf(w3blk[j][d], w1c[d], c);
                v[j] = (__bf16)(w2gt[j] * c);
            }
            const int f = (kb_s * 128 + n) * 4 + q_s;
            *(bf16x8*)&sGTs[(f ^ ((f >> 7) & 7)) * 8] = v;   // swizzled slot
        }
    }
    // ---- Phase B: W2s staging (2*W2, frag-swizzled) ----
    {
        float w2blk[8][8];                 // W2 rows k0..k0+7, cols n0..n0+7
        #pragma unroll
        for (int j = 0; j < 8; ++j) {
            const float4 a = *(const float4*)(W2g + (k0 + j) * 128 + n0);
            const float4 b = *(const float4*)(W2g + (k0 + j) * 128 + n0 + 4);
            w2blk[j][0] = a.x; w2blk[j][1] = a.y; w2blk[j][2] = a.z; w2blk[j][3] = a.w;
            w2blk[j][4] = b.x; w2blk[j][5] = b.y; w2blk[j][6] = b.z; w2blk[j][7] = b.w;
        }
        #pragma unroll
        for (int nn = 0; nn < 8; ++nn) {
            const int nnr = (nn + tc) & 7;
            bf16x8 v;
            #pragma unroll
            for (int j = 0; j < 8; ++j) v[j] = (__bf16)(2.0f * w2blk[j][nnr]);
            const int f = (kb_s * 128 + n0 + nnr) * 4 + q_s;
            *(bf16x8*)&sW2s[(f ^ ((f >> 7) & 7)) * 8] = v;   // swizzled slot
        }
    }

    __bf16* T = tile[w];
    const bf16x8* W2sv = (const bf16x8*)sW2s;
    const bf16x8* GTsv = (const bf16x8*)sGTs;

    float4 zn0a, zn1a, zn0b, zn1b;   // prefetched z for it 1

    #pragma unroll 1
    for (int it = 0; it < 2; ++it) {
        const int sbase = blockIdx.x * 256 + it * 128 + w * 32;

        // ---- build B-frags of X^T: lane holds x[sample p][k=q*8+j] ----
        bf16x8 ax0, ax1;
        #pragma unroll
        for (int j = 0; j < 8; ++j) { ax0[j] = (__bf16)0.0f; ax1[j] = (__bf16)0.0f; }
        if (q == 0) {
            ax0[0] = (__bf16)zc0a.x; ax0[1] = (__bf16)zc0a.y;
            ax0[2] = (__bf16)zc0a.z; ax0[3] = (__bf16)zc0a.w;
            ax0[4] = (__bf16)zc1a.x; ax0[5] = (__bf16)zc1a.y;
            ax0[6] = (__bf16)zc1a.z; ax0[7] = (__bf16)zc1a.w;
            ax1[0] = (__bf16)zc0b.x; ax1[1] = (__bf16)zc0b.y;
            ax1[2] = (__bf16)zc0b.z; ax1[3] = (__bf16)zc0b.w;
            ax1[4] = (__bf16)zc1b.x; ax1[5] = (__bf16)zc1b.y;
            ax1[6] = (__bf16)zc1b.z; ax1[7] = (__bf16)zc1b.w;
        } else if (q == 1) {
            ax0[0] = (__bf16)tval; ax0[1] = (__bf16)1.0f; ax0[2] = (__bf16)1.0f;
            ax1[0] = (__bf16)tval; ax1[1] = (__bf16)1.0f; ax1[2] = (__bf16)1.0f;
        }

        // ---- GEMM0: 2*h1pre = mfma(2W1^T-frag, X^T-frag); bias via K-slots ----
        float a1c0[32], a1c1[32];
        bf16x8 aha[4], ahb[4];
        #pragma unroll
        for (int h = 0; h < 2; ++h) {
            floatx4 accA[4], accB[4];
            #pragma unroll
            for (int lt = 0; lt < 4; ++lt) {
                const floatx4 zz = {0.f, 0.f, 0.f, 0.f};
                accA[lt] = __builtin_amdgcn_mfma_f32_16x16x32_bf16(w1f[4 * h + lt], ax0, zz, 0, 0, 0);
                accB[lt] = __builtin_amdgcn_mfma_f32_16x16x32_bf16(w1f[4 * h + lt], ax1, zz, 0, 0, 0);
            }
            #pragma unroll
            for (int lt = 0; lt < 4; ++lt) {            // group a epilogue
                bf16x4 v;
                #pragma unroll
                for (int r = 0; r < 4; ++r) {
                    const float h1 = fast_tanh2(accA[lt][r]);
                    a1c0[(4 * h + lt) * 4 + r] = __builtin_fmaf(-h1, h1, 1.0f);
                    v[r] = (__bf16)h1;
                }
                *(bf16x4*)&T[p * PITCH_H + lt * 16 + q * 4] = v;   // contiguous b64
            }
            // wave-private in-order DS: write->read round-trip safe, no barrier
            aha[2 * h]     = *(const bf16x8*)&T[p * PITCH_H + q * 8];
            aha[2 * h + 1] = *(const bf16x8*)&T[p * PITCH_H + 32 + q * 8];
            #pragma unroll
            for (int lt = 0; lt < 4; ++lt) {            // group b epilogue (tile reused)
                bf16x4 v;
                #pragma unroll
                for (int r = 0; r < 4; ++r) {
                    const float h1 = fast_tanh2(accB[lt][r]);
                    a1c1[(4 * h + lt) * 4 + r] = __builtin_fmaf(-h1, h1, 1.0f);
                    v[r] = (__bf16)h1;
                }
                *(bf16x4*)&T[p * PITCH_H + lt * 16 + q * 4] = v;
            }
            ahb[2 * h]     = *(const bf16x8*)&T[p * PITCH_H + q * 8];
            ahb[2 * h + 1] = *(const bf16x8*)&T[p * PITCH_H + 32 + q * 8];
        }

        if (it == 0) {
            // prefetch z for it 1: latency hides under GEMM1+GEMM2
            if (q == 0) {
                const int sb1i = blockIdx.x * 256 + 128 + w * 32;
                const float4* zp0 = (const float4*)(z + (size_t)(sb1i + p) * 8);
                const float4* zp1 = (const float4*)(z + (size_t)(sb1i + 16 + p) * 8);
                zn0a = zp0[0]; zn1a = zp0[1]; zn0b = zp1[0]; zn1b = zp1[1];
            }
            // single barrier: all threads' staging writes visible before GEMM1
            __syncthreads();
        }

        // ---- GEMM1: 2*h2pre = mfma(2W2^T-frag, h1^T-frag, C=2b2); shared W2 reads ----
        bf16x8 ah2a[4], ah2b[4];
        #pragma unroll
        for (int h = 0; h < 2; ++h) {
            floatx4 accA[4], accB[4];
            #pragma unroll
            for (int lt = 0; lt < 4; ++lt) {
                const int nt = 4 * h + lt;
                const floatx4 binit = *(const floatx4*)&sb2f[nt * 16 + q * 4]; // broadcast
                floatx4 a = binit, b = binit;
                #pragma unroll
                for (int kb = 0; kb < 4; ++kb) {
                    // slot XOR const: ((f>>7)&7) == (4*kb + (nt>>1)) & 7 (lane-independent)
                    const int f = (kb * 128 + nt * 16 + p) * 4 + q;
                    const bf16x8 wf = W2sv[f ^ ((4 * kb + (nt >> 1)) & 7)];
                    a = __builtin_amdgcn_mfma_f32_16x16x32_bf16(wf, aha[kb], a, 0, 0, 0);
                    b = __builtin_amdgcn_mfma_f32_16x16x32_bf16(wf, ahb[kb], b, 0, 0, 0);
                }
                accA[lt] = a; accB[lt] = b;
            }
            #pragma unroll
            for (int lt = 0; lt < 4; ++lt) {            // group a epilogue
                bf16x4 v;
                #pragma unroll
                for (int r = 0; r < 4; ++r) v[r] = (__bf16)fast_tanh2(accA[lt][r]);
                *(bf16x4*)&T[p * PITCH_H + lt * 16 + q * 4] = v;
            }
            ah2a[2 * h]     = *(const bf16x8*)&T[p * PITCH_H + q * 8];
            ah2a[2 * h + 1] = *(const bf16x8*)&T[p * PITCH_H + 32 + q * 8];
            #pragma unroll
            for (int lt = 0; lt < 4; ++lt) {            // group b epilogue
                bf16x4 v;
                #pragma unroll
                for (int r = 0; r < 4; ++r) v[r] = (__bf16)fast_tanh2(accB[lt][r]);
                *(bf16x4*)&T[p * PITCH_H + lt * 16 + q * 4] = v;
            }
            ah2b[2 * h]     = *(const bf16x8*)&T[p * PITCH_H + q * 8];
            ah2b[2 * h + 1] = *(const bf16x8*)&T[p * PITCH_H + 32 + q * 8];
        }

        // ---- GEMM3: dz^T = mfma(W3^T-frag, h2^T-frag, C=b3); float4 store ----
        floatx4 d3A = b3f, d3B = b3f;
        #pragma unroll
        for (int kb = 0; kb < 4; ++kb) {
            d3A = __builtin_amdgcn_mfma_f32_16x16x32_bf16(w3f[kb], ah2a[kb], d3A, 0, 0, 0);
            d3B = __builtin_amdgcn_mfma_f32_16x16x32_bf16(w3f[kb], ah2b[kb], d3B, 0, 0, 0);
        }
        if (q < 2) {
            *(floatx4*)(out + (size_t)(sbase + p) * 8 + q * 4) = d3A;
            *(floatx4*)(out + (size_t)(sbase + 16 + p) * 8 + q * 4) = d3B;
        }

        // a2 A-frags in-register: a2 = 1 - h2^2 (elementwise in k)
        bf16x8 aaA[4], aaB[4];
        #pragma unroll
        for (int kb = 0; kb < 4; ++kb) {
            #pragma unroll
            for (int j = 0; j < 8; ++j) {
                const float fa = (float)ah2a[kb][j];
                aaA[kb][j] = (__bf16)__builtin_fmaf(-fa, fa, 1.0f);
                const float fb = (float)ah2b[kb][j];
                aaB[kb][j] = (__bf16)__builtin_fmaf(-fb, fb, 1.0f);
            }
        }

        // ---- GEMM2: U^T = mfma(G-frag, a2^T-frag); trace scalar/lane ----
        float trA = 0.f, trB = 0.f;
        #pragma unroll
        for (int nt = 0; nt < 8; ++nt) {
            floatx4 uA = {0.f, 0.f, 0.f, 0.f}, uB = {0.f, 0.f, 0.f, 0.f};
            #pragma unroll
            for (int kb = 0; kb < 4; ++kb) {
                const int f = (kb * 128 + nt * 16 + p) * 4 + q;
                const bf16x8 gf = GTsv[f ^ ((4 * kb + (nt >> 1)) & 7)];
                uA = __builtin_amdgcn_mfma_f32_16x16x32_bf16(gf, aaA[kb], uA, 0, 0, 0);
                uB = __builtin_amdgcn_mfma_f32_16x16x32_bf16(gf, aaB[kb], uB, 0, 0, 0);
            }
            #pragma unroll
            for (int r = 0; r < 4; ++r) {
                trA = __builtin_fmaf(a1c0[nt * 4 + r], uA[r], trA);
                trB = __builtin_fmaf(a1c1[nt * 4 + r], uB[r], trB);
            }
        }
        trA += __shfl_xor(trA, 16, 64);
        trA += __shfl_xor(trA, 32, 64);
        trB += __shfl_xor(trB, 16, 64);
        trB += __shfl_xor(trB, 32, 64);
        if (lane < 16) {
            out[(size_t)BATCH * 8 + sbase + p] = -trA;
            out[(size_t)BATCH * 8 + sbase + 16 + p] = -trB;
        }

        // rotate prefetched z into current
        if (it == 0) { zc0a = zn0a; zc1a = zn1a; zc0b = zn0b; zc1b = zn1b; }
    }
}

extern "C" void kernel_launch(void* const* d_in, const int* in_sizes, int n_in,
                              void* d_out, int out_size, void* d_ws, size_t ws_size,
                              hipStream_t stream) {
    const float* z  = (const float*)d_in[0];
    // d_in[1] = logp_z (unused by the reference math)
    const float* t  = (const float*)d_in[2];
    const float* W1 = (const float*)d_in[3];
    const float* b1 = (const float*)d_in[4];
    const float* W2 = (const float*)d_in[5];
    const float* b2 = (const float*)d_in[6];
    const float* W3 = (const float*)d_in[7];
    const float* b3 = (const float*)d_in[8];
    float* out = (float*)d_out;

    // single self-contained launch: fragments built in-kernel from raw weights
    cnf_main<<<512, 256, 0, stream>>>(z, t, W1, b1, W2, b2, W3, b3, out);
}

// Round 17
// 107.113 us; speedup vs baseline: 1.1576x; 1.1576x over previous
//
#include <hip/hip_runtime.h>
#include <hip/hip_bf16.h>

#define BATCH 131072
#define PITCH_H 72   // half-tile row: 64 + 8 pad bf16 (144 B = 9x16B; rows stay 16B-aligned)

typedef __bf16 bf16x4 __attribute__((ext_vector_type(4)));
typedef __bf16 bf16x8 __attribute__((ext_vector_type(8)));
typedef float floatx4 __attribute__((ext_vector_type(4)));

// Weights carry the tanh's factor 2 (exact in FP: bf16(2w) == 2*bf16(w)), so
// the GEMM output y equals 2*preact bit-exactly and tanh needs no input mul:
// tanh = 1 - 2/(exp(y)+1); exp overflow -> inf -> rcp -> 0 -> +1 (correct limit)
__device__ __forceinline__ float fast_tanh2(float y) {
    float e = __expf(y);
    return 1.0f - 2.0f * __builtin_amdgcn_rcpf(e + 1.0f);
}

// Fragment index: f = (kb*128 + n)*4 + q  <->  M[k = kb*32 + q*8 + j][n], j=0..7.
// STORAGE SLOT (R17 bank-deconflict): slot(f) = f ^ ((f>>5)&7)   [bijective]
//  - WRITE side (staging, n = tc*8+nn): (f>>5)&7 == tc&7, which spans 0..7
//    across each consecutive 8-lane group (q_s, tc>>3 fixed) -> the 8 lanes
//    hit 8 DISTINCT 16B slots -> conflict-free b128 writes. (R16's (f>>7)&7
//    collapsed against q_s within a wave -> still 16-way; measured 2.1M.)
//  - READ side (n = nt*16+p): (f>>5)&7 == ((2*nt)&7) | (p>>3) -- compile-time
//    const OR a per-lane bit; one XOR per read; conflict profile identical
//    to R12's DMA-linear layout (measured fine at 393K).
//  - NO runtime array indexing anywhere (R16's nnr rotation put the staging
//    arrays in scratch: WRITE_SIZE 43MB, rule #20). All loops compile-time.
// Operand-swap symmetry: A-frag of M^T == B-frag of M for mfma_16x16x32.
//
// Structure rationale (rounds 0-16 evidence):
//  - Single launch saves ~9us fixed overhead (R15: 59.5 -> 50.6).
//  - All other levers measured: occupancy null (R7), stagger null (R9),
//    LDS-share +2 (R10), operand-swap +4.4 (R11), DMA staging +1.9 (R12),
//    VALU-count null (R13), I-cache null (R14).
//  - LDS = 32(W2)+32(GT)+9(tiles)+0.5(b2) = 73.5 KB -> 2 blocks/CU.
//  - launch_bounds(256,2) ONLY: budget-256 is the proven spill-free regime.
//  - ESCAPE HATCH: if cnf >= 45us here, revert to R12 structure.
__global__ __launch_bounds__(256, 2) void cnf_main(
        const float* __restrict__ z, const float* __restrict__ t_ptr,
        const float* __restrict__ W1g, const float* __restrict__ b1g,
        const float* __restrict__ W2g, const float* __restrict__ b2g,
        const float* __restrict__ W3g, const float* __restrict__ b3g,
        float* __restrict__ out) {
    __shared__ __bf16 sW2s[16384];                             // 32 KB
    __shared__ __bf16 sGTs[16384];                             // 32 KB
    __shared__ float sb2f[128];                                // 512 B (holds 2*b2)
    __shared__ __align__(16) __bf16 tile[4][16 * PITCH_H];     // 9 KB

    const int tid = threadIdx.x;
    const int lane = tid & 63;
    const int w = tid >> 6;
    const int p = lane & 15;       // sample index (C/D col in all GEMMs)
    const int q = lane >> 4;       // quad (C/D row group)
    const int ph = p >> 3;         // read-side slot-XOR lane bit
    const float tval = t_ptr[0];

    // staging-tile coords: thread handles k in [k0,k0+8) x n in [n0,n0+8)
    const int tr = tid >> 4, tc = tid & 15;
    const int k0 = tr * 8, n0 = tc * 8;
    const int kb_s = tr >> 2, q_s = tr & 3;   // k0..k0+7 spans ONE swizzle octet

    // ---- hoisted data loads ----
    // z for it 0 (q==0 lanes)
    float4 zc0a, zc1a, zc0b, zc1b;
    {
        const int sb0 = blockIdx.x * 256 + w * 32;
        if (q == 0) {
            const float4* zp0 = (const float4*)(z + (size_t)(sb0 + p) * 8);
            const float4* zp1 = (const float4*)(z + (size_t)(sb0 + 16 + p) * 8);
            zc0a = zp0[0]; zc1a = zp0[1]; zc0b = zp1[0]; zc1b = zp1[1];
        }
    }

    // w1f from raw W1/b1 (x2 fold; bias hi/lo in K-slots 9/10) - bit-identical
    bf16x8 w1f[8];
    #pragma unroll
    for (int nt = 0; nt < 8; ++nt) {
        const int n = nt * 16 + p;
        bf16x8 v;
        #pragma unroll
        for (int j = 0; j < 8; ++j) v[j] = (__bf16)0.0f;
        if (q == 0) {
            #pragma unroll
            for (int j = 0; j < 8; ++j) v[j] = (__bf16)(2.0f * W1g[j * 128 + n]);
        } else if (q == 1) {
            v[0] = (__bf16)(2.0f * W1g[8 * 128 + n]);
            const float b2x = 2.0f * b1g[n];
            const float hi = (float)(__bf16)b2x;
            v[1] = (__bf16)b2x;          // bias hi
            v[2] = (__bf16)(b2x - hi);   // bias lo
        }
        w1f[nt] = v;
    }
    // w3f from raw W3 (unscaled; n=p<8 real, else 0)
    bf16x8 w3f[4];
    #pragma unroll
    for (int kb = 0; kb < 4; ++kb) {
        bf16x8 v;
        #pragma unroll
        for (int j = 0; j < 8; ++j)
            v[j] = (p < 8) ? (__bf16)W3g[(kb * 32 + q * 8 + j) * 8 + p] : (__bf16)0.0f;
        w3f[kb] = v;
    }
    floatx4 b3f = {0.f, 0.f, 0.f, 0.f};
    if (q < 2) b3f = *(const floatx4*)(b3g + q * 4);   // dz rows q*4+r (real d<8)
    if (tid < 128) sb2f[tid] = 2.0f * b2g[tid];        // x2 fold

    // ---- Phase A: GT staging. GT[k][n] = W2[n][k] * C[k][n], C = W3@W1 ----
    {
        float w3blk[8][8];                 // W3 rows k0..k0+7 (contiguous 256 B)
        #pragma unroll
        for (int j = 0; j < 8; ++j) {
            const float4 a = *(const float4*)(W3g + (k0 + j) * 8);
            const float4 b = *(const float4*)(W3g + (k0 + j) * 8 + 4);
            w3blk[j][0] = a.x; w3blk[j][1] = a.y; w3blk[j][2] = a.z; w3blk[j][3] = a.w;
            w3blk[j][4] = b.x; w3blk[j][5] = b.y; w3blk[j][6] = b.z; w3blk[j][7] = b.w;
        }
        #pragma unroll
        for (int nn = 0; nn < 8; ++nn) {   // compile-time only (rule #20)
            const int n = n0 + nn;
            float w1c[8];
            #pragma unroll
            for (int d = 0; d < 8; ++d) w1c[d] = W1g[d * 128 + n];
            const float4 g0 = *(const float4*)(W2g + n * 128 + k0);
            const float4 g1 = *(const float4*)(W2g + n * 128 + k0 + 4);
            const float w2gt[8] = {g0.x, g0.y, g0.z, g0.w, g1.x, g1.y, g1.z, g1.w};
            bf16x8 v;
            #pragma unroll
            for (int j = 0; j < 8; ++j) {
                float c = 0.0f;
                #pragma unroll
                for (int d = 0; d < 8; ++d) c = __builtin_fmaf(w3blk[j][d], w1c[d], c);
                v[j] = (__bf16)(w2gt[j] * c);
            }
            const int f = (kb_s * 128 + n) * 4 + q_s;
            *(bf16x8*)&sGTs[(f ^ ((f >> 5) & 7)) * 8] = v;   // conflict-free slot
        }
    }
    // ---- Phase B: W2s staging (2*W2, frag-swizzled) ----
    {
        float w2blk[8][8];                 // W2 rows k0..k0+7, cols n0..n0+7
        #pragma unroll
        for (int j = 0; j < 8; ++j) {
            const float4 a = *(const float4*)(W2g + (k0 + j) * 128 + n0);
            const float4 b = *(const float4*)(W2g + (k0 + j) * 128 + n0 + 4);
            w2blk[j][0] = a.x; w2blk[j][1] = a.y; w2blk[j][2] = a.z; w2blk[j][3] = a.w;
            w2blk[j][4] = b.x; w2blk[j][5] = b.y; w2blk[j][6] = b.z; w2blk[j][7] = b.w;
        }
        #pragma unroll
        for (int nn = 0; nn < 8; ++nn) {   // compile-time only
            bf16x8 v;
            #pragma unroll
            for (int j = 0; j < 8; ++j) v[j] = (__bf16)(2.0f * w2blk[j][nn]);
            const int f = (kb_s * 128 + n0 + nn) * 4 + q_s;
            *(bf16x8*)&sW2s[(f ^ ((f >> 5) & 7)) * 8] = v;   // conflict-free slot
        }
    }

    __bf16* T = tile[w];
    const bf16x8* W2sv = (const bf16x8*)sW2s;
    const bf16x8* GTsv = (const bf16x8*)sGTs;

    float4 zn0a, zn1a, zn0b, zn1b;   // prefetched z for it 1

    #pragma unroll 1
    for (int it = 0; it < 2; ++it) {
        const int sbase = blockIdx.x * 256 + it * 128 + w * 32;

        // ---- build B-frags of X^T: lane holds x[sample p][k=q*8+j] ----
        bf16x8 ax0, ax1;
        #pragma unroll
        for (int j = 0; j < 8; ++j) { ax0[j] = (__bf16)0.0f; ax1[j] = (__bf16)0.0f; }
        if (q == 0) {
            ax0[0] = (__bf16)zc0a.x; ax0[1] = (__bf16)zc0a.y;
            ax0[2] = (__bf16)zc0a.z; ax0[3] = (__bf16)zc0a.w;
            ax0[4] = (__bf16)zc1a.x; ax0[5] = (__bf16)zc1a.y;
            ax0[6] = (__bf16)zc1a.z; ax0[7] = (__bf16)zc1a.w;
            ax1[0] = (__bf16)zc0b.x; ax1[1] = (__bf16)zc0b.y;
            ax1[2] = (__bf16)zc0b.z; ax1[3] = (__bf16)zc0b.w;
            ax1[4] = (__bf16)zc1b.x; ax1[5] = (__bf16)zc1b.y;
            ax1[6] = (__bf16)zc1b.z; ax1[7] = (__bf16)zc1b.w;
        } else if (q == 1) {
            ax0[0] = (__bf16)tval; ax0[1] = (__bf16)1.0f; ax0[2] = (__bf16)1.0f;
            ax1[0] = (__bf16)tval; ax1[1] = (__bf16)1.0f; ax1[2] = (__bf16)1.0f;
        }

        // ---- GEMM0: 2*h1pre = mfma(2W1^T-frag, X^T-frag); bias via K-slots ----
        float a1c0[32], a1c1[32];
        bf16x8 aha[4], ahb[4];
        #pragma unroll
        for (int h = 0; h < 2; ++h) {
            floatx4 accA[4], accB[4];
            #pragma unroll
            for (int lt = 0; lt < 4; ++lt) {
                const floatx4 zz = {0.f, 0.f, 0.f, 0.f};
                accA[lt] = __builtin_amdgcn_mfma_f32_16x16x32_bf16(w1f[4 * h + lt], ax0, zz, 0, 0, 0);
                accB[lt] = __builtin_amdgcn_mfma_f32_16x16x32_bf16(w1f[4 * h + lt], ax1, zz, 0, 0, 0);
            }
            #pragma unroll
            for (int lt = 0; lt < 4; ++lt) {            // group a epilogue
                bf16x4 v;
                #pragma unroll
                for (int r = 0; r < 4; ++r) {
                    const float h1 = fast_tanh2(accA[lt][r]);
                    a1c0[(4 * h + lt) * 4 + r] = __builtin_fmaf(-h1, h1, 1.0f);
                    v[r] = (__bf16)h1;
                }
                *(bf16x4*)&T[p * PITCH_H + lt * 16 + q * 4] = v;   // contiguous b64
            }
            // wave-private in-order DS: write->read round-trip safe, no barrier
            aha[2 * h]     = *(const bf16x8*)&T[p * PITCH_H + q * 8];
            aha[2 * h + 1] = *(const bf16x8*)&T[p * PITCH_H + 32 + q * 8];
            #pragma unroll
            for (int lt = 0; lt < 4; ++lt) {            // group b epilogue (tile reused)
                bf16x4 v;
                #pragma unroll
                for (int r = 0; r < 4; ++r) {
                    const float h1 = fast_tanh2(accB[lt][r]);
                    a1c1[(4 * h + lt) * 4 + r] = __builtin_fmaf(-h1, h1, 1.0f);
                    v[r] = (__bf16)h1;
                }
                *(bf16x4*)&T[p * PITCH_H + lt * 16 + q * 4] = v;
            }
            ahb[2 * h]     = *(const bf16x8*)&T[p * PITCH_H + q * 8];
            ahb[2 * h + 1] = *(const bf16x8*)&T[p * PITCH_H + 32 + q * 8];
        }

        if (it == 0) {
            // prefetch z for it 1: latency hides under GEMM1+GEMM2
            if (q == 0) {
                const int sb1i = blockIdx.x * 256 + 128 + w * 32;
                const float4* zp0 = (const float4*)(z + (size_t)(sb1i + p) * 8);
                const float4* zp1 = (const float4*)(z + (size_t)(sb1i + 16 + p) * 8);
                zn0a = zp0[0]; zn1a = zp0[1]; zn0b = zp1[0]; zn1b = zp1[1];
            }
            // single barrier: all threads' staging writes visible before GEMM1
            __syncthreads();
        }

        // ---- GEMM1: 2*h2pre = mfma(2W2^T-frag, h1^T-frag, C=2b2); shared W2 reads ----
        bf16x8 ah2a[4], ah2b[4];
        #pragma unroll
        for (int h = 0; h < 2; ++h) {
            floatx4 accA[4], accB[4];
            #pragma unroll
            for (int lt = 0; lt < 4; ++lt) {
                const int nt = 4 * h + lt;
                const int xr = ((2 * nt) & 7) | ph;      // read-side slot XOR
                const floatx4 binit = *(const floatx4*)&sb2f[nt * 16 + q * 4]; // broadcast
                floatx4 a = binit, b = binit;
                #pragma unroll
                for (int kb = 0; kb < 4; ++kb) {
                    const int f = (kb * 128 + nt * 16 + p) * 4 + q;
                    const bf16x8 wf = W2sv[f ^ xr];
                    a = __builtin_amdgcn_mfma_f32_16x16x32_bf16(wf, aha[kb], a, 0, 0, 0);
                    b = __builtin_amdgcn_mfma_f32_16x16x32_bf16(wf, ahb[kb], b, 0, 0, 0);
                }
                accA[lt] = a; accB[lt] = b;
            }
            #pragma unroll
            for (int lt = 0; lt < 4; ++lt) {            // group a epilogue
                bf16x4 v;
                #pragma unroll
                for (int r = 0; r < 4; ++r) v[r] = (__bf16)fast_tanh2(accA[lt][r]);
                *(bf16x4*)&T[p * PITCH_H + lt * 16 + q * 4] = v;
            }
            ah2a[2 * h]     = *(const bf16x8*)&T[p * PITCH_H + q * 8];
            ah2a[2 * h + 1] = *(const bf16x8*)&T[p * PITCH_H + 32 + q * 8];
            #pragma unroll
            for (int lt = 0; lt < 4; ++lt) {            // group b epilogue
                bf16x4 v;
                #pragma unroll
                for (int r = 0; r < 4; ++r) v[r] = (__bf16)fast_tanh2(accB[lt][r]);
                *(bf16x4*)&T[p * PITCH_H + lt * 16 + q * 4] = v;
            }
            ah2b[2 * h]     = *(const bf16x8*)&T[p * PITCH_H + q * 8];
            ah2b[2 * h + 1] = *(const bf16x8*)&T[p * PITCH_H + 32 + q * 8];
        }

        // ---- GEMM3: dz^T = mfma(W3^T-frag, h2^T-frag, C=b3); float4 store ----
        floatx4 d3A = b3f, d3B = b3f;
        #pragma unroll
        for (int kb = 0; kb < 4; ++kb) {
            d3A = __builtin_amdgcn_mfma_f32_16x16x32_bf16(w3f[kb], ah2a[kb], d3A, 0, 0, 0);
            d3B = __builtin_amdgcn_mfma_f32_16x16x32_bf16(w3f[kb], ah2b[kb], d3B, 0, 0, 0);
        }
        if (q < 2) {
            *(floatx4*)(out + (size_t)(sbase + p) * 8 + q * 4) = d3A;
            *(floatx4*)(out + (size_t)(sbase + 16 + p) * 8 + q * 4) = d3B;
        }

        // a2 A-frags in-register: a2 = 1 - h2^2 (elementwise in k)
        bf16x8 aaA[4], aaB[4];
        #pragma unroll
        for (int kb = 0; kb < 4; ++kb) {
            #pragma unroll
            for (int j = 0; j < 8; ++j) {
                const float fa = (float)ah2a[kb][j];
                aaA[kb][j] = (__bf16)__builtin_fmaf(-fa, fa, 1.0f);
                const float fb = (float)ah2b[kb][j];
                aaB[kb][j] = (__bf16)__builtin_fmaf(-fb, fb, 1.0f);
            }
        }

        // ---- GEMM2: U^T = mfma(G-frag, a2^T-frag); trace scalar/lane ----
        float trA = 0.f, trB = 0.f;
        #pragma unroll
        for (int nt = 0; nt < 8; ++nt) {
            const int xr = ((2 * nt) & 7) | ph;          // read-side slot XOR
            floatx4 uA = {0.f, 0.f, 0.f, 0.f}, uB = {0.f, 0.f, 0.f, 0.f};
            #pragma unroll
            for (int kb = 0; kb < 4; ++kb) {
                const int f = (kb * 128 + nt * 16 + p) * 4 + q;
                const bf16x8 gf = GTsv[f ^ xr];
                uA = __builtin_amdgcn_mfma_f32_16x16x32_bf16(gf, aaA[kb], uA, 0, 0, 0);
                uB = __builtin_amdgcn_mfma_f32_16x16x32_bf16(gf, aaB[kb], uB, 0, 0, 0);
            }
            #pragma unroll
            for (int r = 0; r < 4; ++r) {
                trA = __builtin_fmaf(a1c0[nt * 4 + r], uA[r], trA);
                trB = __builtin_fmaf(a1c1[nt * 4 + r], uB[r], trB);
            }
        }
        trA += __shfl_xor(trA, 16, 64);
        trA += __shfl_xor(trA, 32, 64);
        trB += __shfl_xor(trB, 16, 64);
        trB += __shfl_xor(trB, 32, 64);
        if (lane < 16) {
            out[(size_t)BATCH * 8 + sbase + p] = -trA;
            out[(size_t)BATCH * 8 + sbase + 16 + p] = -trB;
        }

        // rotate prefetched z into current
        if (it == 0) { zc0a = zn0a; zc1a = zn1a; zc0b = zn0b; zc1b = zn1b; }
    }
}

extern "C" void kernel_launch(void* const* d_in, const int* in_sizes, int n_in,
                              void* d_out, int out_size, void* d_ws, size_t ws_size,
                              hipStream_t stream) {
    const float* z  = (const float*)d_in[0];
    // d_in[1] = logp_z (unused by the reference math)
    const float* t  = (const float*)d_in[2];
    const float* W1 = (const float*)d_in[3];
    const float* b1 = (const float*)d_in[4];
    const float* W2 = (const float*)d_in[5];
    const float* b2 = (const float*)d_in[6];
    const float* W3 = (const float*)d_in[7];
    const float* b3 = (const float*)d_in[8];
    float* out = (float*)d_out;

    // single self-contained launch: fragments built in-kernel from raw weights
    cnf_main<<<512, 256, 0, stream>>>(z, t, W1, b1, W2, b2, W3, b3, out);
}

// Round 18
// 88.075 us; speedup vs baseline: 1.4078x; 1.2162x over previous
//
#include <hip/hip_runtime.h>
#include <hip/hip_bf16.h>

#define BATCH 131072
#define PITCH_H 72   // half-tile row: 64 + 8 pad bf16 (144 B = 9x16B; rows stay 16B-aligned)

typedef __bf16 bf16x4 __attribute__((ext_vector_type(4)));
typedef __bf16 bf16x8 __attribute__((ext_vector_type(8)));
typedef float floatx4 __attribute__((ext_vector_type(4)));

#define GLOBAL_AS __attribute__((address_space(1)))
#define LDS_AS __attribute__((address_space(3)))

__device__ __forceinline__ float fast_tanh(float x) {
    // tanh(x) = 1 - 2/(exp(2x)+1); exp overflow -> inf -> rcp -> 0 -> +1 (correct limit)
    float e = __expf(2.0f * x);
    return 1.0f - 2.0f * __builtin_amdgcn_rcpf(e + 1.0f);
}

// d_ws element layout (bf16):
// [0,16384)       W2s : frag-swizzled W2                (GEMM1)
// [16384,32768)   GTs : frag-swizzled G^T, G=W2*C^T     (GEMM2)
// [32768,36864)   W1s : frag-swizzled W1, K pad to 32; rows k=9,10 carry b1 hi/lo (GEMM0)
// [36864,38912)   W3s : frag-swizzled W3, N pad to 16   (GEMM3)
// swizzle: idx = ((kb*N + n)*4 + q)*8 + j  <->  M[k = kb*32 + q*8 + j][n]
// Operand-swap symmetry: A-frag of M^T == B-frag of M for mfma_16x16x32, so
// these fragments serve the transposed GEMMs with no prep change.

__global__ void prep_kernel(const float* __restrict__ W1,
                            const float* __restrict__ W2,
                            const float* __restrict__ W3,
                            const float* __restrict__ b1,
                            __bf16* __restrict__ ws) {
    int idx = blockIdx.x * 256 + threadIdx.x;
    if (idx < 16384) {
        int j = idx & 7, q = (idx >> 3) & 3, n = (idx >> 5) & 127, kb = idx >> 12;
        int k = kb * 32 + q * 8 + j;
        ws[idx] = (__bf16)W2[k * 128 + n];
        float c = 0.0f;
        #pragma unroll
        for (int d = 0; d < 8; ++d) c += W3[k * 8 + d] * W1[d * 128 + n];
        ws[16384 + idx] = (__bf16)(W2[n * 128 + k] * c);
    } else if (idx < 20480) {
        int t = idx - 16384;
        int j = t & 7, q = (t >> 3) & 3, n = t >> 5;   // kb==0 only
        int k = q * 8 + j;
        __bf16 v = (__bf16)0.0f;
        if (k < 9) v = (__bf16)W1[k * 128 + n];
        else if (k == 9) v = (__bf16)b1[n];                    // bias hi (x[9]=1)
        else if (k == 10) {                                    // bias lo (x[10]=1)
            float hi = (float)(__bf16)b1[n];
            v = (__bf16)(b1[n] - hi);
        }
        ws[32768 + t] = v;
    } else if (idx < 22528) {
        int t = idx - 20480;
        int j = t & 7, q = (t >> 3) & 3, n = (t >> 5) & 15, kb = t >> 9;
        int k = kb * 32 + q * 8 + j;
        ws[36864 + t] = (n < 8) ? (__bf16)W3[k * 8 + n] : (__bf16)0.0f;
    }
}

// Structure rationale (rounds 0-17 evidence) — this is the R12 best (88.0us):
//  - Operand-swap transposed GEMMs (R11, +4.4us): D=[hidden][sample];
//    contiguous b64 tile writes, biases via K-slots/C-operand, scalar trace.
//  - DMA staging (global_load_lds) of W2+GT overlapped with GEMM0; single
//    residency round (512 blocks x 2 its); z prefetch for it1 (R12, +1.9us).
//  - In-kernel fused staging (R15-R17) saved the prep launch (~9us) but cost
//    13-22us inside the kernel (bank conflicts + codegen scratch) — reverted.
//  - Measured nulls: occupancy (R7), stagger (R9), VALU-count (R13),
//    I-cache (R14). cnf ~28.5us is a latency plateau with no saturated pipe.
//  - LDS = 32(W2)+32(GT)+9(tiles)+0.5(b2) = 73.5 KB -> 2 blocks/CU.
//  - launch_bounds(256,2) ONLY: budget-256 is the proven spill-free regime.
//    min-waves>=4 attrs -> 64-VGPR acc-split + ~200 MB scratch spill (R1/R2).
__global__ __launch_bounds__(256, 2) void cnf_main(
        const float* __restrict__ z, const float* __restrict__ t_ptr,
        const float* __restrict__ b1g, const float* __restrict__ b2g,
        const float* __restrict__ b3g, const __bf16* __restrict__ ws,
        float* __restrict__ out) {
    __shared__ __bf16 sW2s[16384];                             // 32 KB
    __shared__ __bf16 sGTs[16384];                             // 32 KB
    __shared__ float sb2f[128];                                // 512 B
    __shared__ __align__(16) __bf16 tile[4][16 * PITCH_H];     // 9 KB

    const int tid = threadIdx.x;
    const int lane = tid & 63;
    const int w = tid >> 6;
    const int p = lane & 15;       // sample index (C/D col in all GEMMs)
    const int q = lane >> 4;       // quad (C/D row group)
    const float tval = t_ptr[0];

    // ---- hoisted scalar/frag loads (issue before DMA; GEMM0 needs them) ----
    const bf16x8* W1g = (const bf16x8*)(ws + 32768);
    const bf16x8* W3g = (const bf16x8*)(ws + 36864);
    bf16x8 w1f[8];
    #pragma unroll
    for (int nt = 0; nt < 8; ++nt) w1f[nt] = W1g[(nt * 16 + p) * 4 + q];
    bf16x8 w3f[4];
    #pragma unroll
    for (int kb = 0; kb < 4; ++kb) w3f[kb] = W3g[(kb * 16 + p) * 4 + q];
    floatx4 b3f = {0.f, 0.f, 0.f, 0.f};
    if (q < 2) b3f = *(const floatx4*)(b3g + q * 4);   // dz rows q*4+r (real d<8)
    const float b2v = (tid < 128) ? b2g[tid] : 0.0f;

    // z for it 0 (q==0 lanes; latency hides under DMA issue + GEMM0 prep)
    float4 zc0a, zc1a, zc0b, zc1b;
    {
        const int sb0 = blockIdx.x * 256 + w * 32;
        if (q == 0) {
            const float4* zp0 = (const float4*)(z + (size_t)(sb0 + p) * 8);
            const float4* zp1 = (const float4*)(z + (size_t)(sb0 + 16 + p) * 8);
            zc0a = zp0[0]; zc1a = zp0[1]; zc0b = zp1[0]; zc1b = zp1[1];
        }
    }

    // ---- async DMA staging of W2 + GT (linear, wave-uniform base + lane*16) ----
    {
        const uint4* srcW2v = (const uint4*)ws;
        const uint4* srcGTv = (const uint4*)(ws + 16384);
        uint4* dstW2v = (uint4*)sW2s;
        uint4* dstGTv = (uint4*)sGTs;
        #pragma unroll
        for (int i = 0; i < 8; ++i) {
            const int idx = tid + i * 256;
            const int wbase = w * 64 + i * 256;   // wave-uniform uint4 index
            __builtin_amdgcn_global_load_lds(
                (const GLOBAL_AS uint4*)(srcW2v + idx),
                (LDS_AS uint4*)(dstW2v + wbase), 16, 0, 0);
            __builtin_amdgcn_global_load_lds(
                (const GLOBAL_AS uint4*)(srcGTv + idx),
                (LDS_AS uint4*)(dstGTv + wbase), 16, 0, 0);
        }
    }

    __bf16* T = tile[w];
    const bf16x8* W2sv = (const bf16x8*)sW2s;
    const bf16x8* GTsv = (const bf16x8*)sGTs;

    float4 zn0a, zn1a, zn0b, zn1b;   // prefetched z for it 1

    #pragma unroll
    for (int it = 0; it < 2; ++it) {
        const int sbase = blockIdx.x * 256 + it * 128 + w * 32;

        // ---- build B-frags of X^T: lane holds x[sample p][k=q*8+j] ----
        bf16x8 ax0, ax1;
        #pragma unroll
        for (int j = 0; j < 8; ++j) { ax0[j] = (__bf16)0.0f; ax1[j] = (__bf16)0.0f; }
        if (q == 0) {
            ax0[0] = (__bf16)zc0a.x; ax0[1] = (__bf16)zc0a.y;
            ax0[2] = (__bf16)zc0a.z; ax0[3] = (__bf16)zc0a.w;
            ax0[4] = (__bf16)zc1a.x; ax0[5] = (__bf16)zc1a.y;
            ax0[6] = (__bf16)zc1a.z; ax0[7] = (__bf16)zc1a.w;
            ax1[0] = (__bf16)zc0b.x; ax1[1] = (__bf16)zc0b.y;
            ax1[2] = (__bf16)zc0b.z; ax1[3] = (__bf16)zc0b.w;
            ax1[4] = (__bf16)zc1b.x; ax1[5] = (__bf16)zc1b.y;
            ax1[6] = (__bf16)zc1b.z; ax1[7] = (__bf16)zc1b.w;
        } else if (q == 1) {
            ax0[0] = (__bf16)tval; ax0[1] = (__bf16)1.0f; ax0[2] = (__bf16)1.0f;
            ax1[0] = (__bf16)tval; ax1[1] = (__bf16)1.0f; ax1[2] = (__bf16)1.0f;
        }

        // ---- GEMM0: h1^T = mfma(W1^T-frag, X^T-frag); bias via K-slots ----
        float a1c0[32], a1c1[32];
        bf16x8 aha[4], ahb[4];
        #pragma unroll
        for (int h = 0; h < 2; ++h) {
            floatx4 accA[4], accB[4];
            #pragma unroll
            for (int lt = 0; lt < 4; ++lt) {
                const floatx4 zz = {0.f, 0.f, 0.f, 0.f};
                accA[lt] = __builtin_amdgcn_mfma_f32_16x16x32_bf16(w1f[4 * h + lt], ax0, zz, 0, 0, 0);
                accB[lt] = __builtin_amdgcn_mfma_f32_16x16x32_bf16(w1f[4 * h + lt], ax1, zz, 0, 0, 0);
            }
            #pragma unroll
            for (int lt = 0; lt < 4; ++lt) {            // group a epilogue
                bf16x4 v;
                #pragma unroll
                for (int r = 0; r < 4; ++r) {
                    const float h1 = fast_tanh(accA[lt][r]);
                    a1c0[(4 * h + lt) * 4 + r] = __builtin_fmaf(-h1, h1, 1.0f);
                    v[r] = (__bf16)h1;
                }
                *(bf16x4*)&T[p * PITCH_H + lt * 16 + q * 4] = v;   // contiguous b64
            }
            // wave-private in-order DS: write->read round-trip safe, no barrier
            aha[2 * h]     = *(const bf16x8*)&T[p * PITCH_H + q * 8];
            aha[2 * h + 1] = *(const bf16x8*)&T[p * PITCH_H + 32 + q * 8];
            #pragma unroll
            for (int lt = 0; lt < 4; ++lt) {            // group b epilogue (tile reused)
                bf16x4 v;
                #pragma unroll
                for (int r = 0; r < 4; ++r) {
                    const float h1 = fast_tanh(accB[lt][r]);
                    a1c1[(4 * h + lt) * 4 + r] = __builtin_fmaf(-h1, h1, 1.0f);
                    v[r] = (__bf16)h1;
                }
                *(bf16x4*)&T[p * PITCH_H + lt * 16 + q * 4] = v;
            }
            ahb[2 * h]     = *(const bf16x8*)&T[p * PITCH_H + q * 8];
            ahb[2 * h + 1] = *(const bf16x8*)&T[p * PITCH_H + 32 + q * 8];
        }

        if (it == 0) {
            // prefetch z for it 1: latency hides under GEMM1+GEMM2
            if (q == 0) {
                const int sb1i = blockIdx.x * 256 + 128 + w * 32;
                const float4* zp0 = (const float4*)(z + (size_t)(sb1i + p) * 8);
                const float4* zp1 = (const float4*)(z + (size_t)(sb1i + 16 + p) * 8);
                zn0a = zp0[0]; zn1a = zp0[1]; zn0b = zp1[0]; zn1b = zp1[1];
            }
            // b2 -> LDS, then the single barrier (drains staging DMA via vmcnt)
            if (tid < 128) sb2f[tid] = b2v;
            __syncthreads();
        }

        // ---- GEMM1: h2^T = mfma(W2^T-frag, h1^T-frag, C=b2); shared W2 reads ----
        bf16x8 ah2a[4], ah2b[4];
        #pragma unroll
        for (int h = 0; h < 2; ++h) {
            floatx4 accA[4], accB[4];
            #pragma unroll
            for (int lt = 0; lt < 4; ++lt) {
                const int nt = 4 * h + lt;
                const floatx4 binit = *(const floatx4*)&sb2f[nt * 16 + q * 4]; // broadcast
                floatx4 a = binit, b = binit;
                #pragma unroll
                for (int kb = 0; kb < 4; ++kb) {
                    const bf16x8 wf = W2sv[(kb * 128 + nt * 16 + p) * 4 + q];
                    a = __builtin_amdgcn_mfma_f32_16x16x32_bf16(wf, aha[kb], a, 0, 0, 0);
                    b = __builtin_amdgcn_mfma_f32_16x16x32_bf16(wf, ahb[kb], b, 0, 0, 0);
                }
                accA[lt] = a; accB[lt] = b;
            }
            #pragma unroll
            for (int lt = 0; lt < 4; ++lt) {            // group a epilogue
                bf16x4 v;
                #pragma unroll
                for (int r = 0; r < 4; ++r) v[r] = (__bf16)fast_tanh(accA[lt][r]);
                *(bf16x4*)&T[p * PITCH_H + lt * 16 + q * 4] = v;
            }
            ah2a[2 * h]     = *(const bf16x8*)&T[p * PITCH_H + q * 8];
            ah2a[2 * h + 1] = *(const bf16x8*)&T[p * PITCH_H + 32 + q * 8];
            #pragma unroll
            for (int lt = 0; lt < 4; ++lt) {            // group b epilogue
                bf16x4 v;
                #pragma unroll
                for (int r = 0; r < 4; ++r) v[r] = (__bf16)fast_tanh(accB[lt][r]);
                *(bf16x4*)&T[p * PITCH_H + lt * 16 + q * 4] = v;
            }
            ah2b[2 * h]     = *(const bf16x8*)&T[p * PITCH_H + q * 8];
            ah2b[2 * h + 1] = *(const bf16x8*)&T[p * PITCH_H + 32 + q * 8];
        }

        // ---- GEMM3: dz^T = mfma(W3^T-frag, h2^T-frag, C=b3); float4 store ----
        floatx4 d3A = b3f, d3B = b3f;
        #pragma unroll
        for (int kb = 0; kb < 4; ++kb) {
            d3A = __builtin_amdgcn_mfma_f32_16x16x32_bf16(w3f[kb], ah2a[kb], d3A, 0, 0, 0);
            d3B = __builtin_amdgcn_mfma_f32_16x16x32_bf16(w3f[kb], ah2b[kb], d3B, 0, 0, 0);
        }
        if (q < 2) {
            *(floatx4*)(out + (size_t)(sbase + p) * 8 + q * 4) = d3A;
            *(floatx4*)(out + (size_t)(sbase + 16 + p) * 8 + q * 4) = d3B;
        }

        // a2 A-frags in-register: a2 = 1 - h2^2 (elementwise in k)
        bf16x8 aaA[4], aaB[4];
        #pragma unroll
        for (int kb = 0; kb < 4; ++kb) {
            #pragma unroll
            for (int j = 0; j < 8; ++j) {
                const float fa = (float)ah2a[kb][j];
                aaA[kb][j] = (__bf16)__builtin_fmaf(-fa, fa, 1.0f);
                const float fb = (float)ah2b[kb][j];
                aaB[kb][j] = (__bf16)__builtin_fmaf(-fb, fb, 1.0f);
            }
        }

        // ---- GEMM2: U^T = mfma(G-frag, a2^T-frag); trace scalar/lane ----
        float trA = 0.f, trB = 0.f;
        #pragma unroll
        for (int nt = 0; nt < 8; ++nt) {
            floatx4 uA = {0.f, 0.f, 0.f, 0.f}, uB = {0.f, 0.f, 0.f, 0.f};
            #pragma unroll
            for (int kb = 0; kb < 4; ++kb) {
                const bf16x8 gf = GTsv[(kb * 128 + nt * 16 + p) * 4 + q];
                uA = __builtin_amdgcn_mfma_f32_16x16x32_bf16(gf, aaA[kb], uA, 0, 0, 0);
                uB = __builtin_amdgcn_mfma_f32_16x16x32_bf16(gf, aaB[kb], uB, 0, 0, 0);
            }
            #pragma unroll
            for (int r = 0; r < 4; ++r) {
                trA = __builtin_fmaf(a1c0[nt * 4 + r], uA[r], trA);
                trB = __builtin_fmaf(a1c1[nt * 4 + r], uB[r], trB);
            }
        }
        trA += __shfl_xor(trA, 16, 64);
        trA += __shfl_xor(trA, 32, 64);
        trB += __shfl_xor(trB, 16, 64);
        trB += __shfl_xor(trB, 32, 64);
        if (lane < 16) {
            out[(size_t)BATCH * 8 + sbase + p] = -trA;
            out[(size_t)BATCH * 8 + sbase + 16 + p] = -trB;
        }

        // rotate prefetched z into current
        if (it == 0) { zc0a = zn0a; zc1a = zn1a; zc0b = zn0b; zc1b = zn1b; }
    }
}

extern "C" void kernel_launch(void* const* d_in, const int* in_sizes, int n_in,
                              void* d_out, int out_size, void* d_ws, size_t ws_size,
                              hipStream_t stream) {
    const float* z  = (const float*)d_in[0];
    // d_in[1] = logp_z (unused by the reference math)
    const float* t  = (const float*)d_in[2];
    const float* W1 = (const float*)d_in[3];
    const float* b1 = (const float*)d_in[4];
    const float* W2 = (const float*)d_in[5];
    const float* b2 = (const float*)d_in[6];
    const float* W3 = (const float*)d_in[7];
    const float* b3 = (const float*)d_in[8];
    __bf16* ws = (__bf16*)d_ws;
    float* out = (float*)d_out;

    prep_kernel<<<88, 256, 0, stream>>>(W1, W2, W3, b1, ws);
    cnf_main<<<512, 256, 0, stream>>>(z, t, b1, b2, b3, ws, out);
}